// Round 12
// baseline (2140.480 us; speedup 1.0000x reference)
//
#include <hip/hip_runtime.h>

#define BB 8
#define NN 8192
#define NPOINT 2048
#define NSAMPLE 32
#define CC 64

typedef float v2f __attribute__((ext_vector_type(2)));

// ---------------- kernel 0a: transpose features (B,C,N) -> (B,N,C) ----------
__global__ __launch_bounds__(256) void k_transpose(const float* __restrict__ f,
                                                   float* __restrict__ ft) {
  __shared__ float tile[64][65];
  int b = blockIdx.y;
  int p0 = blockIdx.x * 64;
  int tx = threadIdx.x, ty = threadIdx.y;
  const float* fb = f + (size_t)b * CC * NN;
#pragma unroll
  for (int i = 0; i < 16; ++i) {
    int c = i * 4 + ty;
    tile[c][tx] = fb[(size_t)c * NN + p0 + tx];
  }
  __syncthreads();
  float* fo = ft + ((size_t)b * NN + p0) * CC;
#pragma unroll
  for (int i = 0; i < 16; ++i) {
    int pl = i * 4 + ty;
    fo[(size_t)pl * CC + tx] = tile[tx][pl];
  }
}

// ---------------- kernel 0b: permute/pad W1 (64,67) -> (64,68) --------------
__global__ void k_permW1(const float* __restrict__ W1, float* __restrict__ W1p) {
  int i = blockIdx.x * 256 + threadIdx.x;
  if (i < 64 * 68) {
    int o = i / 68, k = i % 68;
    float v;
    if (k < 64) v = W1[o * 67 + 3 + k];
    else if (k < 67) v = W1[o * 67 + (k - 64)];
    else v = 0.0f;
    W1p[i] = v;
  }
}

// ---------------- kernel 1: furthest point sampling (exact) -----------------
// r12: r8 champion structure (256 thr / 4 waves, short quad_perm tail, LDS-only
// in-loop stores) + ONE fused VOP3P asm block per point-pair for the distance
// chain. Theory: the v2f operator code half-scalarizes (r8 VALU-issue ~2x the
// packed ideal); r4's per-op asm failed via boundary copies, so fuse all 8
// packed ops into a single block with early-clobber outs. v_pk_add/mul are
// IEEE rn, no contraction; px + (-cx) == px - cx bit-exact.
#define DPPMAX(var, ctrl)                                                       \
  {                                                                             \
    unsigned long long _b = (unsigned long long)__double_as_longlong(var);      \
    int _lo = __builtin_amdgcn_update_dpp(0, (int)(unsigned)_b, ctrl, 0xf, 0xf, \
                                          false);                               \
    int _hi = __builtin_amdgcn_update_dpp(0, (int)(unsigned)(_b >> 32), ctrl,   \
                                          0xf, 0xf, false);                     \
    double _s = __longlong_as_double(                                           \
        (long long)(((unsigned long long)(unsigned)_hi << 32) | (unsigned)_lo));\
    var = fmax(var, _s);                                                        \
  }

__global__ __launch_bounds__(256, 1) void k_fps(const float* __restrict__ xyz,
                                                float* __restrict__ newxyz) {
  __shared__ __align__(16) float4 sxyz[NN];  // 128 KB
  __shared__ float swin[3 * NPOINT];         // 24 KB winner coords
  __shared__ __align__(16) double wkey[2][4];
  int b = blockIdx.x;
  const float* X = xyz + (size_t)b * NN * 3;
  int t = threadIdx.x;
  int lane = t & 63;
  v2f px[16], py[16], pz[16], dd[16];
#pragma unroll
  for (int j = 0; j < 16; ++j) {
    int p0 = t + (2 * j) * 256, p1 = p0 + 256;
    float x0 = X[p0 * 3 + 0], y0 = X[p0 * 3 + 1], z0 = X[p0 * 3 + 2];
    float x1 = X[p1 * 3 + 0], y1 = X[p1 * 3 + 1], z1 = X[p1 * 3 + 2];
    px[j].x = x0; px[j].y = x1;
    py[j].x = y0; py[j].y = y1;
    pz[j].x = z0; pz[j].y = z1;
    sxyz[p0] = make_float4(x0, y0, z0, 0.0f);
    sxyz[p1] = make_float4(x1, y1, z1, 0.0f);
    dd[j].x = __builtin_inff(); dd[j].y = __builtin_inff();
  }
  __syncthreads();
  float cx, cy, cz;
  {
    float4 c0 = sxyz[0];
    cx = c0.x; cy = c0.y; cz = c0.z;
  }
  if (t == 0) { swin[0] = cx; swin[1] = cy; swin[2] = cz; }
  for (int it = 1; it < NPOINT; ++it) {
#pragma clang fp contract(off)
    // negated center splats: p + (-c) == p - c exactly
    float ncx = -cx, ncy = -cy, ncz = -cz;
    v2f ncx2, ncy2, ncz2;
    ncx2.x = ncx; ncx2.y = ncx;
    ncy2.x = ncy; ncy2.y = ncy;
    ncz2.x = ncz; ncz2.y = ncz;
    float m0 = -1.0f, m1 = -1.0f;
    int k0 = 0, k1 = 0;  // winning unroll index per chain
#pragma unroll
    for (int j = 0; j < 16; ++j) {
      v2f d, yy, zz;
      // fused packed chain: dx=px-c; dy;dz; squares; (xx+yy)+zz (numpy order)
      asm("v_pk_add_f32 %0, %3, %6\n\t"
          "v_pk_add_f32 %1, %4, %7\n\t"
          "v_pk_add_f32 %2, %5, %8\n\t"
          "v_pk_mul_f32 %0, %0, %0\n\t"
          "v_pk_mul_f32 %1, %1, %1\n\t"
          "v_pk_mul_f32 %2, %2, %2\n\t"
          "v_pk_add_f32 %0, %0, %1\n\t"
          "v_pk_add_f32 %0, %0, %2"
          : "=&v"(d), "=&v"(yy), "=&v"(zz)
          : "v"(px[j]), "v"(py[j]), "v"(pz[j]), "v"(ncx2), "v"(ncy2),
            "v"(ncz2));
      v2f nd;
      nd.x = fminf(dd[j].x, d.x);
      nd.y = fminf(dd[j].y, d.y);
      dd[j] = nd;
      if (nd.x > m0) { m0 = nd.x; k0 = j; }  // strict > => lowest j => lowest idx
      if (nd.y > m1) { m1 = nd.y; k1 = j; }
    }
    // exact global indices: p = t + 256*(2j+half)
    unsigned i0 = (unsigned)(t + (k0 << 9));
    unsigned i1 = (unsigned)(t + (k1 << 9) + 256);
    // pack (dist_bits<<32 | ~idx): u64 order == f64 order (positive, no NaN)
    double best = __longlong_as_double(
        (long long)(((unsigned long long)__float_as_uint(m0) << 32) | ~i0));
    double c1 = __longlong_as_double(
        (long long)(((unsigned long long)__float_as_uint(m1) << 32) | ~i1));
    best = fmax(best, c1);
    DPPMAX(best, 0x111)  // row_shr:1
    DPPMAX(best, 0x112)  // row_shr:2
    DPPMAX(best, 0x114)  // row_shr:4
    DPPMAX(best, 0x118)  // row_shr:8
    DPPMAX(best, 0x142)  // row_bcast:15
    DPPMAX(best, 0x143)  // row_bcast:31
    int sel = it & 1;
    if (lane == 63) wkey[sel][t >> 6] = best;  // lane 63 = wave max
    __syncthreads();
    // cross-wave: each lane reads ONE wave-slot, quad_perm butterfly max
    double gk = wkey[sel][lane & 3];
    DPPMAX(gk, 0xB1)  // quad_perm [1,0,3,2]
    DPPMAX(gk, 0x4E)  // quad_perm [2,3,0,1]
    unsigned wi = ~(unsigned)(unsigned long long)__double_as_longlong(gk);
    float4 cw = sxyz[wi];
    cx = cw.x; cy = cw.y; cz = cw.z;
    if (t == 0) {  // LDS only inside the loop
      swin[3 * it + 0] = cx;
      swin[3 * it + 1] = cy;
      swin[3 * it + 2] = cz;
    }
  }
  __syncthreads();
  float* ob = newxyz + (size_t)b * 3 * NPOINT;
#pragma unroll
  for (int i = 0; i < 24; ++i) ob[t + i * 256] = swin[t + i * 256];
}

// ------- kernel 2: fused ball query + gather + 3-layer MLP + maxpool --------
__global__ __launch_bounds__(256) void k_mlp(
    const float* __restrict__ featsT, const float* __restrict__ xyz,
    const float* __restrict__ newxyz,
    const float* __restrict__ W1p, const float* __restrict__ b1,
    const float* __restrict__ W2, const float* __restrict__ b2,
    const float* __restrict__ W3, const float* __restrict__ b3,
    float* __restrict__ outf) {
  __shared__ __align__(16) float xb[4][32][68];  // 34.8 KB
  __shared__ int lidx[4][32];
  int w = threadIdx.x >> 6, lane = threadIdx.x & 63;
  int g = blockIdx.x * 4 + w;
  int b = g >> 11, s2 = g & 2047;
  const float* X = xyz + (size_t)b * NN * 3;
  const float* cp = newxyz + (((size_t)b << 11) + s2) * 3;
  float ccx = cp[0], ccy = cp[1], ccz = cp[2];

  // ---- fused ball query (exact, first-32 ascending) ----
  {
    const float r2 = 0.2f * 0.2f;
    int found = 0;
    for (int ch = 0; ch < NN / 64; ++ch) {
      int p = ch * 64 + lane;
      float x = X[p * 3 + 0], y = X[p * 3 + 1], z = X[p * 3 + 2];
      float dx = __fsub_rn(ccx, x);
      float dy = __fsub_rn(ccy, y);
      float dz = __fsub_rn(ccz, z);
      float d2 = __fadd_rn(__fadd_rn(__fmul_rn(dx, dx), __fmul_rn(dy, dy)),
                           __fmul_rn(dz, dz));
      bool in = d2 < r2;
      unsigned long long m = __ballot(in);
      int rank = __popcll(m & ((1ull << lane) - 1ull));
      int slot = found + rank;
      if (in && slot < NSAMPLE) lidx[w][slot] = p;
      found += __popcll(m);
      if (found >= NSAMPLE) break;
    }
    int nf = found < NSAMPLE ? found : NSAMPLE;
    int sl = lane & 31, half = lane >> 5;
    int p = (nf == 0) ? 0 : lidx[w][sl < nf ? sl : 0];
    const float4* src = (const float4*)(featsT + (((size_t)b << 13) + p) * 64);
    float4* dst = (float4*)&xb[w][sl][0];
    if (half == 0) {
#pragma unroll
      for (int kt = 0; kt < 8; ++kt) dst[kt] = src[kt];
    } else {
#pragma unroll
      for (int kt = 8; kt < 16; ++kt) dst[kt] = src[kt];
      const float* pp = X + p * 3;
      float dx = __fsub_rn(pp[0], ccx);
      float dy = __fsub_rn(pp[1], ccy);
      float dz = __fsub_rn(pp[2], ccz);
      dst[16] = make_float4(dx, dy, dz, 0.0f);
    }
  }
  int si = lane & 3, oi = lane >> 2;
  float* xrow0 = &xb[w][0][0];
  float acc[4][8];

  // ---- layer 1: K=68 ----
#pragma unroll
  for (int r = 0; r < 4; ++r) {
    float bv = b1[oi * 4 + r];
#pragma unroll
    for (int q = 0; q < 8; ++q) acc[r][q] = bv;
  }
  for (int kt = 0; kt < 17; ++kt) {
    float4 wv[4];
#pragma unroll
    for (int r = 0; r < 4; ++r)
      wv[r] = *(const float4*)(W1p + (oi * 4 + r) * 68 + kt * 4);
#pragma unroll
    for (int q = 0; q < 8; ++q) {
      float4 xv = *(const float4*)(xrow0 + (si + 4 * q) * 68 + kt * 4);
#pragma unroll
      for (int r = 0; r < 4; ++r) {
        acc[r][q] = fmaf(wv[r].x, xv.x, acc[r][q]);
        acc[r][q] = fmaf(wv[r].y, xv.y, acc[r][q]);
        acc[r][q] = fmaf(wv[r].z, xv.z, acc[r][q]);
        acc[r][q] = fmaf(wv[r].w, xv.w, acc[r][q]);
      }
    }
  }
#pragma unroll
  for (int q = 0; q < 8; ++q) {
    int s = si + 4 * q;
    float4 v = make_float4(fmaxf(acc[0][q], 0.f), fmaxf(acc[1][q], 0.f),
                           fmaxf(acc[2][q], 0.f), fmaxf(acc[3][q], 0.f));
    *(float4*)(xrow0 + s * 68 + oi * 4) = v;
  }

  // ---- layer 2: K=64 ----
#pragma unroll
  for (int r = 0; r < 4; ++r) {
    float bv = b2[oi * 4 + r];
#pragma unroll
    for (int q = 0; q < 8; ++q) acc[r][q] = bv;
  }
  for (int kt = 0; kt < 16; ++kt) {
    float4 wv[4];
#pragma unroll
    for (int r = 0; r < 4; ++r)
      wv[r] = *(const float4*)(W2 + (oi * 4 + r) * 64 + kt * 4);
#pragma unroll
    for (int q = 0; q < 8; ++q) {
      float4 xv = *(const float4*)(xrow0 + (si + 4 * q) * 68 + kt * 4);
#pragma unroll
      for (int r = 0; r < 4; ++r) {
        acc[r][q] = fmaf(wv[r].x, xv.x, acc[r][q]);
        acc[r][q] = fmaf(wv[r].y, xv.y, acc[r][q]);
        acc[r][q] = fmaf(wv[r].z, xv.z, acc[r][q]);
        acc[r][q] = fmaf(wv[r].w, xv.w, acc[r][q]);
      }
    }
  }
#pragma unroll
  for (int q = 0; q < 8; ++q) {
    int s = si + 4 * q;
    float4 v = make_float4(fmaxf(acc[0][q], 0.f), fmaxf(acc[1][q], 0.f),
                           fmaxf(acc[2][q], 0.f), fmaxf(acc[3][q], 0.f));
    *(float4*)(xrow0 + s * 68 + oi * 4) = v;
  }

  // ---- layer 3: K=64, 128 outputs (two passes) + maxpool ----
  float accB[4][8];
#pragma unroll
  for (int r = 0; r < 4; ++r) {
    float bvA = b3[oi * 4 + r];
    float bvB = b3[64 + oi * 4 + r];
#pragma unroll
    for (int q = 0; q < 8; ++q) { acc[r][q] = bvA; accB[r][q] = bvB; }
  }
  for (int kt = 0; kt < 16; ++kt) {
    float4 wa[4], wb[4];
#pragma unroll
    for (int r = 0; r < 4; ++r) {
      wa[r] = *(const float4*)(W3 + (oi * 4 + r) * 64 + kt * 4);
      wb[r] = *(const float4*)(W3 + (64 + oi * 4 + r) * 64 + kt * 4);
    }
#pragma unroll
    for (int q = 0; q < 8; ++q) {
      float4 xv = *(const float4*)(xrow0 + (si + 4 * q) * 68 + kt * 4);
#pragma unroll
      for (int r = 0; r < 4; ++r) {
        acc[r][q] = fmaf(wa[r].x, xv.x, acc[r][q]);
        acc[r][q] = fmaf(wa[r].y, xv.y, acc[r][q]);
        acc[r][q] = fmaf(wa[r].z, xv.z, acc[r][q]);
        acc[r][q] = fmaf(wa[r].w, xv.w, acc[r][q]);
        accB[r][q] = fmaf(wb[r].x, xv.x, accB[r][q]);
        accB[r][q] = fmaf(wb[r].y, xv.y, accB[r][q]);
        accB[r][q] = fmaf(wb[r].z, xv.z, accB[r][q]);
        accB[r][q] = fmaf(wb[r].w, xv.w, accB[r][q]);
      }
    }
  }
#pragma unroll
  for (int r = 0; r < 4; ++r) {
    float mA = acc[r][0], mB = accB[r][0];
#pragma unroll
    for (int q = 1; q < 8; ++q) {
      mA = fmaxf(mA, acc[r][q]);
      mB = fmaxf(mB, accB[r][q]);
    }
    mA = fmaxf(mA, __shfl_xor(mA, 1));
    mA = fmaxf(mA, __shfl_xor(mA, 2));
    mB = fmaxf(mB, __shfl_xor(mB, 1));
    mB = fmaxf(mB, __shfl_xor(mB, 2));
    mA = fmaxf(mA, 0.0f);
    mB = fmaxf(mB, 0.0f);
    if (si == 0) {
      int o = oi * 4 + r;
      outf[(((size_t)b * 128 + o) << 11) + s2] = mA;
      outf[(((size_t)b * 128 + o + 64) << 11) + s2] = mB;
    }
  }
}

extern "C" void kernel_launch(void* const* d_in, const int* in_sizes, int n_in,
                              void* d_out, int out_size, void* d_ws, size_t ws_size,
                              hipStream_t stream) {
  const float* xyz = (const float*)d_in[0];
  const float* feats = (const float*)d_in[1];
  const float* W1 = (const float*)d_in[2];
  const float* b1 = (const float*)d_in[3];
  const float* W2 = (const float*)d_in[4];
  const float* b2 = (const float*)d_in[5];
  const float* W3 = (const float*)d_in[6];
  const float* b3 = (const float*)d_in[7];
  float* out_newxyz = (float*)d_out;
  float* out_feats = (float*)d_out + (size_t)BB * NPOINT * 3;

  char* ws = (char*)d_ws;
  float* featsT = (float*)ws;                        // 16 MB
  float* W1p = (float*)(ws + 16777216);              // 17408 B

  dim3 tb(64, 4);
  k_transpose<<<dim3(NN / 64, BB), tb, 0, stream>>>(feats, featsT);
  k_permW1<<<17, 256, 0, stream>>>(W1, W1p);
  k_fps<<<BB, 256, 0, stream>>>(xyz, out_newxyz);
  k_mlp<<<(BB * NPOINT) / 4, 256, 0, stream>>>(featsT, xyz, out_newxyz,
                                               W1p, b1, W2, b2, W3, b3, out_feats);
}

// Round 13
// 1991.937 us; speedup vs baseline: 1.0746x; 1.0746x over previous
//
#include <hip/hip_runtime.h>

#define BB 8
#define NN 8192
#define NPOINT 2048
#define NSAMPLE 32
#define CC 64

typedef float v2f __attribute__((ext_vector_type(2)));

// ---------------- kernel 0a: transpose features (B,C,N) -> (B,N,C) ----------
__global__ __launch_bounds__(256) void k_transpose(const float* __restrict__ f,
                                                   float* __restrict__ ft) {
  __shared__ float tile[64][65];
  int b = blockIdx.y;
  int p0 = blockIdx.x * 64;
  int tx = threadIdx.x, ty = threadIdx.y;
  const float* fb = f + (size_t)b * CC * NN;
#pragma unroll
  for (int i = 0; i < 16; ++i) {
    int c = i * 4 + ty;
    tile[c][tx] = fb[(size_t)c * NN + p0 + tx];
  }
  __syncthreads();
  float* fo = ft + ((size_t)b * NN + p0) * CC;
#pragma unroll
  for (int i = 0; i < 16; ++i) {
    int pl = i * 4 + ty;
    fo[(size_t)pl * CC + tx] = tile[tx][pl];
  }
}

// ---------------- kernel 0b: permute/pad W1 (64,67) -> (64,68) --------------
__global__ void k_permW1(const float* __restrict__ W1, float* __restrict__ W1p) {
  int i = blockIdx.x * 256 + threadIdx.x;
  if (i < 64 * 68) {
    int o = i / 68, k = i % 68;
    float v;
    if (k < 64) v = W1[o * 67 + 3 + k];
    else if (k < 67) v = W1[o * 67 + (k - 64)];
    else v = 0.0f;
    W1p[i] = v;
  }
}

// ---------------- kernel 1: furthest point sampling (exact) -----------------
// CHAMPION (round 8, 1586us): 256 thr / 4 waves, 32 pts/lane as v2f pairs,
// contract(off) numpy-exact packed math, 6-stage DPP wave reduce on packed
// (dist_bits<<32|~idx) f64 keys (u64 order == f64 order: positive, no NaN),
// short quad_perm cross-wave tail, LDS-only in-loop stores, bulk writeout.
// r9 (lazy), r10 (persistent), r11 (8 waves), r12 (fused asm) all regressed;
// this is the measured practical floor for the serial 2047-iter chain.
#define DPPMAX(var, ctrl)                                                       \
  {                                                                             \
    unsigned long long _b = (unsigned long long)__double_as_longlong(var);      \
    int _lo = __builtin_amdgcn_update_dpp(0, (int)(unsigned)_b, ctrl, 0xf, 0xf, \
                                          false);                               \
    int _hi = __builtin_amdgcn_update_dpp(0, (int)(unsigned)(_b >> 32), ctrl,   \
                                          0xf, 0xf, false);                     \
    double _s = __longlong_as_double(                                           \
        (long long)(((unsigned long long)(unsigned)_hi << 32) | (unsigned)_lo));\
    var = fmax(var, _s);                                                        \
  }

__global__ __launch_bounds__(256, 1) void k_fps(const float* __restrict__ xyz,
                                                float* __restrict__ newxyz) {
  __shared__ __align__(16) float4 sxyz[NN];  // 128 KB
  __shared__ float swin[3 * NPOINT];         // 24 KB winner coords
  __shared__ __align__(16) double wkey[2][4];
  int b = blockIdx.x;
  const float* X = xyz + (size_t)b * NN * 3;
  int t = threadIdx.x;
  int lane = t & 63;
  v2f px[16], py[16], pz[16], dd[16];
#pragma unroll
  for (int j = 0; j < 16; ++j) {
    int p0 = t + (2 * j) * 256, p1 = p0 + 256;
    float x0 = X[p0 * 3 + 0], y0 = X[p0 * 3 + 1], z0 = X[p0 * 3 + 2];
    float x1 = X[p1 * 3 + 0], y1 = X[p1 * 3 + 1], z1 = X[p1 * 3 + 2];
    px[j].x = x0; px[j].y = x1;
    py[j].x = y0; py[j].y = y1;
    pz[j].x = z0; pz[j].y = z1;
    sxyz[p0] = make_float4(x0, y0, z0, 0.0f);
    sxyz[p1] = make_float4(x1, y1, z1, 0.0f);
    dd[j].x = __builtin_inff(); dd[j].y = __builtin_inff();
  }
  __syncthreads();
  float cx, cy, cz;
  {
    float4 c0 = sxyz[0];
    cx = c0.x; cy = c0.y; cz = c0.z;
  }
  if (t == 0) { swin[0] = cx; swin[1] = cy; swin[2] = cz; }
  for (int it = 1; it < NPOINT; ++it) {
#pragma clang fp contract(off)
    v2f vcx, vcy, vcz;
    vcx.x = cx; vcx.y = cx;
    vcy.x = cy; vcy.y = cy;
    vcz.x = cz; vcz.y = cz;
    float m0 = -1.0f, m1 = -1.0f;
    int k0 = 0, k1 = 0;  // winning unroll index per chain
#pragma unroll
    for (int j = 0; j < 16; ++j) {
      v2f dx = px[j] - vcx;  // contract(off): numpy-exact rounding
      v2f dy = py[j] - vcy;
      v2f dz = pz[j] - vcz;
      v2f xx = dx * dx;
      v2f yy = dy * dy;
      v2f zz = dz * dz;
      v2f s = xx + yy;       // numpy order: (x2+y2)+z2
      v2f d = s + zz;
      v2f nd = __builtin_elementwise_min(dd[j], d);
      dd[j] = nd;
      if (nd.x > m0) { m0 = nd.x; k0 = j; }  // strict > => lowest j => lowest idx
      if (nd.y > m1) { m1 = nd.y; k1 = j; }
    }
    // exact global indices: p = t + 256*(2j+half) -> (j,half) lexicographic
    unsigned i0 = (unsigned)(t + (k0 << 9));
    unsigned i1 = (unsigned)(t + (k1 << 9) + 256);
    // pack (dist_bits<<32 | ~idx): u64 order == f64 order (positive, no NaN)
    double best = __longlong_as_double(
        (long long)(((unsigned long long)__float_as_uint(m0) << 32) | ~i0));
    double c1 = __longlong_as_double(
        (long long)(((unsigned long long)__float_as_uint(m1) << 32) | ~i1));
    best = fmax(best, c1);
    DPPMAX(best, 0x111)  // row_shr:1
    DPPMAX(best, 0x112)  // row_shr:2
    DPPMAX(best, 0x114)  // row_shr:4
    DPPMAX(best, 0x118)  // row_shr:8
    DPPMAX(best, 0x142)  // row_bcast:15
    DPPMAX(best, 0x143)  // row_bcast:31
    int sel = it & 1;
    if (lane == 63) wkey[sel][t >> 6] = best;  // lane 63 = wave max
    __syncthreads();
    // cross-wave: each lane reads ONE wave-slot, quad_perm butterfly max
    double gk = wkey[sel][lane & 3];
    DPPMAX(gk, 0xB1)  // quad_perm [1,0,3,2]
    DPPMAX(gk, 0x4E)  // quad_perm [2,3,0,1]
    unsigned wi = ~(unsigned)(unsigned long long)__double_as_longlong(gk);
    float4 cw = sxyz[wi];
    cx = cw.x; cy = cw.y; cz = cw.z;
    if (t == 0) {  // LDS only inside the loop
      swin[3 * it + 0] = cx;
      swin[3 * it + 1] = cy;
      swin[3 * it + 2] = cz;
    }
  }
  __syncthreads();
  // bulk coalesced writeout
  float* ob = newxyz + (size_t)b * 3 * NPOINT;
#pragma unroll
  for (int i = 0; i < 24; ++i) ob[t + i * 256] = swin[t + i * 256];
}

// ------- kernel 2: fused ball query + gather + 3-layer MLP + maxpool --------
__global__ __launch_bounds__(256) void k_mlp(
    const float* __restrict__ featsT, const float* __restrict__ xyz,
    const float* __restrict__ newxyz,
    const float* __restrict__ W1p, const float* __restrict__ b1,
    const float* __restrict__ W2, const float* __restrict__ b2,
    const float* __restrict__ W3, const float* __restrict__ b3,
    float* __restrict__ outf) {
  __shared__ __align__(16) float xb[4][32][68];  // 34.8 KB
  __shared__ int lidx[4][32];
  int w = threadIdx.x >> 6, lane = threadIdx.x & 63;
  int g = blockIdx.x * 4 + w;
  int b = g >> 11, s2 = g & 2047;
  const float* X = xyz + (size_t)b * NN * 3;
  const float* cp = newxyz + (((size_t)b << 11) + s2) * 3;
  float ccx = cp[0], ccy = cp[1], ccz = cp[2];

  // ---- fused ball query (exact, first-32 ascending) ----
  {
    const float r2 = 0.2f * 0.2f;
    int found = 0;
    for (int ch = 0; ch < NN / 64; ++ch) {
      int p = ch * 64 + lane;
      float x = X[p * 3 + 0], y = X[p * 3 + 1], z = X[p * 3 + 2];
      float dx = __fsub_rn(ccx, x);
      float dy = __fsub_rn(ccy, y);
      float dz = __fsub_rn(ccz, z);
      float d2 = __fadd_rn(__fadd_rn(__fmul_rn(dx, dx), __fmul_rn(dy, dy)),
                           __fmul_rn(dz, dz));
      bool in = d2 < r2;
      unsigned long long m = __ballot(in);
      int rank = __popcll(m & ((1ull << lane) - 1ull));
      int slot = found + rank;
      if (in && slot < NSAMPLE) lidx[w][slot] = p;
      found += __popcll(m);
      if (found >= NSAMPLE) break;
    }
    int nf = found < NSAMPLE ? found : NSAMPLE;
    int sl = lane & 31, half = lane >> 5;
    int p = (nf == 0) ? 0 : lidx[w][sl < nf ? sl : 0];
    const float4* src = (const float4*)(featsT + (((size_t)b << 13) + p) * 64);
    float4* dst = (float4*)&xb[w][sl][0];
    if (half == 0) {
#pragma unroll
      for (int kt = 0; kt < 8; ++kt) dst[kt] = src[kt];
    } else {
#pragma unroll
      for (int kt = 8; kt < 16; ++kt) dst[kt] = src[kt];
      const float* pp = X + p * 3;
      float dx = __fsub_rn(pp[0], ccx);
      float dy = __fsub_rn(pp[1], ccy);
      float dz = __fsub_rn(pp[2], ccz);
      dst[16] = make_float4(dx, dy, dz, 0.0f);
    }
  }
  int si = lane & 3, oi = lane >> 2;
  float* xrow0 = &xb[w][0][0];
  float acc[4][8];

  // ---- layer 1: K=68 ----
#pragma unroll
  for (int r = 0; r < 4; ++r) {
    float bv = b1[oi * 4 + r];
#pragma unroll
    for (int q = 0; q < 8; ++q) acc[r][q] = bv;
  }
  for (int kt = 0; kt < 17; ++kt) {
    float4 wv[4];
#pragma unroll
    for (int r = 0; r < 4; ++r)
      wv[r] = *(const float4*)(W1p + (oi * 4 + r) * 68 + kt * 4);
#pragma unroll
    for (int q = 0; q < 8; ++q) {
      float4 xv = *(const float4*)(xrow0 + (si + 4 * q) * 68 + kt * 4);
#pragma unroll
      for (int r = 0; r < 4; ++r) {
        acc[r][q] = fmaf(wv[r].x, xv.x, acc[r][q]);
        acc[r][q] = fmaf(wv[r].y, xv.y, acc[r][q]);
        acc[r][q] = fmaf(wv[r].z, xv.z, acc[r][q]);
        acc[r][q] = fmaf(wv[r].w, xv.w, acc[r][q]);
      }
    }
  }
#pragma unroll
  for (int q = 0; q < 8; ++q) {
    int s = si + 4 * q;
    float4 v = make_float4(fmaxf(acc[0][q], 0.f), fmaxf(acc[1][q], 0.f),
                           fmaxf(acc[2][q], 0.f), fmaxf(acc[3][q], 0.f));
    *(float4*)(xrow0 + s * 68 + oi * 4) = v;
  }

  // ---- layer 2: K=64 ----
#pragma unroll
  for (int r = 0; r < 4; ++r) {
    float bv = b2[oi * 4 + r];
#pragma unroll
    for (int q = 0; q < 8; ++q) acc[r][q] = bv;
  }
  for (int kt = 0; kt < 16; ++kt) {
    float4 wv[4];
#pragma unroll
    for (int r = 0; r < 4; ++r)
      wv[r] = *(const float4*)(W2 + (oi * 4 + r) * 64 + kt * 4);
#pragma unroll
    for (int q = 0; q < 8; ++q) {
      float4 xv = *(const float4*)(xrow0 + (si + 4 * q) * 68 + kt * 4);
#pragma unroll
      for (int r = 0; r < 4; ++r) {
        acc[r][q] = fmaf(wv[r].x, xv.x, acc[r][q]);
        acc[r][q] = fmaf(wv[r].y, xv.y, acc[r][q]);
        acc[r][q] = fmaf(wv[r].z, xv.z, acc[r][q]);
        acc[r][q] = fmaf(wv[r].w, xv.w, acc[r][q]);
      }
    }
  }
#pragma unroll
  for (int q = 0; q < 8; ++q) {
    int s = si + 4 * q;
    float4 v = make_float4(fmaxf(acc[0][q], 0.f), fmaxf(acc[1][q], 0.f),
                           fmaxf(acc[2][q], 0.f), fmaxf(acc[3][q], 0.f));
    *(float4*)(xrow0 + s * 68 + oi * 4) = v;
  }

  // ---- layer 3: K=64, 128 outputs (two passes) + maxpool ----
  float accB[4][8];
#pragma unroll
  for (int r = 0; r < 4; ++r) {
    float bvA = b3[oi * 4 + r];
    float bvB = b3[64 + oi * 4 + r];
#pragma unroll
    for (int q = 0; q < 8; ++q) { acc[r][q] = bvA; accB[r][q] = bvB; }
  }
  for (int kt = 0; kt < 16; ++kt) {
    float4 wa[4], wb[4];
#pragma unroll
    for (int r = 0; r < 4; ++r) {
      wa[r] = *(const float4*)(W3 + (oi * 4 + r) * 64 + kt * 4);
      wb[r] = *(const float4*)(W3 + (64 + oi * 4 + r) * 64 + kt * 4);
    }
#pragma unroll
    for (int q = 0; q < 8; ++q) {
      float4 xv = *(const float4*)(xrow0 + (si + 4 * q) * 68 + kt * 4);
#pragma unroll
      for (int r = 0; r < 4; ++r) {
        acc[r][q] = fmaf(wa[r].x, xv.x, acc[r][q]);
        acc[r][q] = fmaf(wa[r].y, xv.y, acc[r][q]);
        acc[r][q] = fmaf(wa[r].z, xv.z, acc[r][q]);
        acc[r][q] = fmaf(wa[r].w, xv.w, acc[r][q]);
        accB[r][q] = fmaf(wb[r].x, xv.x, accB[r][q]);
        accB[r][q] = fmaf(wb[r].y, xv.y, accB[r][q]);
        accB[r][q] = fmaf(wb[r].z, xv.z, accB[r][q]);
        accB[r][q] = fmaf(wb[r].w, xv.w, accB[r][q]);
      }
    }
  }
#pragma unroll
  for (int r = 0; r < 4; ++r) {
    float mA = acc[r][0], mB = accB[r][0];
#pragma unroll
    for (int q = 1; q < 8; ++q) {
      mA = fmaxf(mA, acc[r][q]);
      mB = fmaxf(mB, accB[r][q]);
    }
    mA = fmaxf(mA, __shfl_xor(mA, 1));
    mA = fmaxf(mA, __shfl_xor(mA, 2));
    mB = fmaxf(mB, __shfl_xor(mB, 1));
    mB = fmaxf(mB, __shfl_xor(mB, 2));
    mA = fmaxf(mA, 0.0f);
    mB = fmaxf(mB, 0.0f);
    if (si == 0) {
      int o = oi * 4 + r;
      outf[(((size_t)b * 128 + o) << 11) + s2] = mA;
      outf[(((size_t)b * 128 + o + 64) << 11) + s2] = mB;
    }
  }
}

extern "C" void kernel_launch(void* const* d_in, const int* in_sizes, int n_in,
                              void* d_out, int out_size, void* d_ws, size_t ws_size,
                              hipStream_t stream) {
  const float* xyz = (const float*)d_in[0];
  const float* feats = (const float*)d_in[1];
  const float* W1 = (const float*)d_in[2];
  const float* b1 = (const float*)d_in[3];
  const float* W2 = (const float*)d_in[4];
  const float* b2 = (const float*)d_in[5];
  const float* W3 = (const float*)d_in[6];
  const float* b3 = (const float*)d_in[7];
  float* out_newxyz = (float*)d_out;
  float* out_feats = (float*)d_out + (size_t)BB * NPOINT * 3;

  char* ws = (char*)d_ws;
  float* featsT = (float*)ws;                        // 16 MB
  float* W1p = (float*)(ws + 16777216);              // 17408 B

  dim3 tb(64, 4);
  k_transpose<<<dim3(NN / 64, BB), tb, 0, stream>>>(feats, featsT);
  k_permW1<<<17, 256, 0, stream>>>(W1, W1p);
  k_fps<<<BB, 256, 0, stream>>>(xyz, out_newxyz);
  k_mlp<<<(BB * NPOINT) / 4, 256, 0, stream>>>(featsT, xyz, out_newxyz,
                                               W1p, b1, W2, b2, W3, b3, out_feats);
}